// Round 2
// baseline (351.137 us; speedup 1.0000x reference)
//
#include <hip/hip_runtime.h>

// entmax-1.5 over rows of an 8192 x 4096 fp32 matrix, boolean mask (int32).
// R10: R8 compute structure (ballot-compacted candidates in LDS, barrier-free
// redundant wave solve with __shfl_xor -- the proven 117 us form; DPP and NT
// stores from R9 reverted as regression) + ROW-LEVEL SOFTWARE PIPELINE.
//
// R9 post-mortem: VALUBusy ~36% == VALU_cy / mem_cy at the achieved BW; no
// pipe saturated -> latency-bound. Each block was a serial chain
// [load 16KB -> wait -> max -> compact -> solve -> store] with memory in
// flight only during the short load window (Little's law starves the CU).
//
// R10 structure:
//  * persistent blocks (grid 2048) pull rows from a global atomic counter in
//    d_ws; oversized grid is harmless (late blocks see counter exhausted and
//    exit). Zero tail imbalance.
//  * while row r runs max/compact/solve/store, row r+1's 8x16B loads are in
//    flight in VGPRs (ps/pm staged regs, converted to z at next row top --
//    the compiler's vmcnt wait lands exactly there).
//  * intra-row barriers are raw s_barrier + lgkmcnt(0) + memory clobber:
//    __syncthreads() would emit s_waitcnt vmcnt(0) before s_barrier and drain
//    the prefetch (guide section 5). LDS ordering only is what we need.
//  * next-row index broadcast through LDS, then readfirstlane -> SGPR base
//    addressing for the prefetch loads (saves addr VGPRs + VALU).
//  * __launch_bounds__(256,6): staged regs push peak to ~75 VGPR; cap ~85
//    avoids the R5/R7 spill cliff. 6 pipelined blocks/CU >= 8 serial ones
//    (measured occupancy was only ~5.5 anyway).

constexpr int NROWS = 8192;
constexpr int NCOL  = 4096;
constexpr int EPT   = 16;   // elements per thread (4096 / 256)
constexpr int NLD   = 4;    // float4/int4 loads per thread
constexpr int CAP   = 128;  // candidate slots per wave region
constexpr int MAXIT = 8;    // solve cap; exact-quadratic typically 2-4 iters
constexpr int GRID  = 2048; // persistent blocks (>= max resident; extras noop)

static __device__ __forceinline__ int mbcnt64(unsigned long long m) {
    // popcount of m restricted to lanes below this lane
    return __builtin_amdgcn_mbcnt_hi((unsigned)(m >> 32),
           __builtin_amdgcn_mbcnt_lo((unsigned)m, 0));
}

// LDS-only barrier: orders ds_read/ds_write across the block WITHOUT draining
// vmcnt -- prefetch global loads stay in flight. The leading asm waits for
// this wave's LDS writes; the trailing empty asm (memory clobber) pins
// post-barrier LDS reads after the barrier.
static __device__ __forceinline__ void lds_barrier() {
    asm volatile("s_waitcnt lgkmcnt(0)" ::: "memory");
    __builtin_amdgcn_s_barrier();
    asm volatile("" ::: "memory");
}

__global__ __launch_bounds__(256, 6)
void entmax15_kernel(const float* __restrict__ scores,
                     const int*   __restrict__ mask,
                     float*       __restrict__ out,
                     unsigned int* __restrict__ rowctr)
{
    __shared__ float cand[4 * CAP];   // wave w owns [w*CAP, (w+1)*CAP)
    __shared__ float redA[4], redB[4];
    __shared__ int   ovfl;
    __shared__ int   rsh[2];          // ping-pong next-row broadcast slots

    const int tid  = threadIdx.x;
    const int lane = tid & 63;
    const int wave = tid >> 6;

    // --- prologue: grab first row, issue its loads ---
    if (tid == 0) rsh[1] = (int)atomicAdd(rowctr, 1u);
    __syncthreads();                  // B0 (nothing in flight; plain barrier ok)
    int row = __builtin_amdgcn_readfirstlane(rsh[1]);
    if (row >= NROWS) return;         // uniform: whole block exits

    float4 ps[NLD];
    int4   pm[NLD];
    {
        const float* srow = scores + (size_t)row * NCOL;
        const int*   mrow = mask   + (size_t)row * NCOL;
        #pragma unroll
        for (int c = 0; c < NLD; ++c) {
            const int base = c * 1024 + tid * 4;
            ps[c] = *reinterpret_cast<const float4*>(srow + base);
            pm[c] = *reinterpret_cast<const int4*>(mrow + base);
        }
    }

    float z[EPT];
    int it = 0;
    #pragma unroll 1
    for (;;) {
        // Fetch next row index (slot it&1; read after B1 -- write/read pairs
        // on each slot are separated by >=2 barriers, no race). Reset per-row
        // LDS state; prev iter's cand/ovfl readers finished before B3.
        if (tid == 0) {
            rsh[it & 1] = (int)atomicAdd(rowctr, 1u);
            ovfl = 0;
        }
        cand[wave * CAP + lane]      = -1e30f;
        cand[wave * CAP + lane + 64] = -1e30f;

        // Convert staged loads -> z (compiler's vmcnt wait lands here).
        #pragma unroll
        for (int c = 0; c < NLD; ++c) {
            z[c * 4 + 0] = pm[c].x ? ps[c].x * 0.5f : -5000.0f;
            z[c * 4 + 1] = pm[c].y ? ps[c].y * 0.5f : -5000.0f;
            z[c * 4 + 2] = pm[c].z ? ps[c].z * 0.5f : -5000.0f;
            z[c * 4 + 3] = pm[c].w ? ps[c].w * 0.5f : -5000.0f;
        }

        // Row max: lane tree, wave butterfly, 4-wave LDS combine.
        float mx = z[0];
        #pragma unroll
        for (int i = 1; i < EPT; ++i) mx = fmaxf(mx, z[i]);
        #pragma unroll
        for (int off = 1; off < 64; off <<= 1)
            mx = fmaxf(mx, __shfl_xor(mx, off, 64));
        if (lane == 0) redA[wave] = mx;
        lds_barrier();                // B1: redA + rsh + sentinels visible
        mx = fmaxf(fmaxf(redA[0], redA[1]), fmaxf(redA[2], redA[3]));
        const float thresh = mx - 1.0f;   // tau* >= thresh

        // PREFETCH: issue next row's loads now; they fly across B2 (raw
        // barrier, no vmcnt drain) and complete under compact+solve+store.
        const int rn = __builtin_amdgcn_readfirstlane(rsh[it & 1]);
        if (rn < NROWS) {
            const float* srow = scores + (size_t)rn * NCOL;
            const int*   mrow = mask   + (size_t)rn * NCOL;
            #pragma unroll
            for (int c = 0; c < NLD; ++c) {
                const int base = c * 1024 + tid * 4;
                ps[c] = *reinterpret_cast<const float4*>(srow + base);
                pm[c] = *reinterpret_cast<const int4*>(mrow + base);
            }
        }

        // Compact candidates into this wave's region: 16 ballot rounds.
        int cnt = 0;
        #pragma unroll
        for (int i = 0; i < EPT; ++i) {
            const bool isc = z[i] > thresh;
            const unsigned long long m = __ballot(isc);
            if (isc) {
                const int pos = cnt + mbcnt64(m);
                if (pos < CAP) cand[wave * CAP + pos] = z[i];
            }
            cnt += (int)__popcll(m);  // wave-uniform
        }
        if (lane == 0 && cnt > CAP) ovfl = 1;
        lds_barrier();                // B2: compaction visible; loads keep flying

        float t = thresh;             // left bracket: g(thresh) >= 0

        if (ovfl == 0) {
            // Barrier-free solve: each wave redundantly reads ALL 512 slots,
            // 8 per lane at stride 64 (conflict-free), sentinels give d=0.
            float cv[8];
            #pragma unroll
            for (int k = 0; k < 8; ++k) cv[k] = cand[k * 64 + lane];

            // Exact piecewise-quadratic iteration (R8-proven form).
            #pragma unroll 1
            for (int itr = 0; itr < MAXIT; ++itr) {
                float s0 = 0.f, s1 = 0.f, s2 = 0.f;
                #pragma unroll
                for (int k = 0; k < 8; ++k) {
                    const float d = fmaxf(cv[k] - t, 0.f);
                    s2 = fmaf(d, d, s2);
                    s1 += d;
                    s0 += (d > 0.f) ? 1.0f : 0.0f;
                }
                #pragma unroll
                for (int off = 1; off < 64; off <<= 1) {
                    s0 += __shfl_xor(s0, off, 64);
                    s1 += __shfl_xor(s1, off, 64);
                    s2 += __shfl_xor(s2, off, 64);
                }
                const float s0c  = fmaxf(s0, 1.0f);     // s0>=1 at t<=tau*<mx
                const float disc = fmaf(s1, s1, -s0c * (s2 - 1.0f));
                const float u    = (s1 - sqrtf(fmaxf(disc, 0.f))) / s0c;
                t += u;                                  // wave-uniform
                if (__builtin_fabsf(u) < 5e-7f) break;   // wave-uniform break
            }
            // All 4 waves computed bit-identical t from identical data.
        } else {
            // Fallback (pathological rows, >>10 sigma): R6-style Newton.
            // Rare path: plain __syncthreads (vmcnt drain acceptable here).
            #pragma unroll 1
            for (int itr = 0; itr < 10; ++itr) {
                float s2 = 0.f, s1 = 0.f;
                #pragma unroll
                for (int i = 0; i < EPT; ++i) {
                    const float d = fmaxf(z[i] - t, 0.f);
                    s2 = fmaf(d, d, s2);
                    s1 += d;
                }
                #pragma unroll
                for (int off = 1; off < 64; off <<= 1) {
                    s2 += __shfl_xor(s2, off, 64);
                    s1 += __shfl_xor(s1, off, 64);
                }
                __syncthreads();
                if (lane == 0) { redA[wave] = s1; redB[wave] = s2; }
                __syncthreads();
                s1 = (redA[0] + redA[1]) + (redA[2] + redA[3]);
                s2 = (redB[0] + redB[1]) + (redB[2] + redB[3]);
                const float step = (s2 - 1.0f) / (2.0f * s1);
                t += step;                                  // block-uniform
                if (__builtin_fabsf(step) < 5e-7f) break;   // block-uniform
            }
        }

        // Epilogue: p = relu(z - tau)^2, coalesced float4 stores (plain --
        // NT stores measured neutral-to-negative in R9).
        {
            float* orow = out + (size_t)row * NCOL;
            #pragma unroll
            for (int c = 0; c < NLD; ++c) {
                const int base = c * 1024 + tid * 4;
                float4 o;
                float d;
                d = fmaxf(z[c * 4 + 0] - t, 0.f); o.x = d * d;
                d = fmaxf(z[c * 4 + 1] - t, 0.f); o.y = d * d;
                d = fmaxf(z[c * 4 + 2] - t, 0.f); o.z = d * d;
                d = fmaxf(z[c * 4 + 3] - t, 0.f); o.w = d * d;
                *reinterpret_cast<float4*>(orow + base) = o;
            }
        }

        if (rn >= NROWS) return;      // uniform: rows exhausted
        lds_barrier();                // B3: cand/ovfl/rsh reads done before
                                      // next iter's writes (loads keep flying)
        row = rn;
        ++it;
    }
}

extern "C" void kernel_launch(void* const* d_in, const int* in_sizes, int n_in,
                              void* d_out, int out_size, void* d_ws, size_t ws_size,
                              hipStream_t stream)
{
    const float* scores = (const float*)d_in[0];
    const int*   mask   = (const int*)d_in[1];
    float*       out    = (float*)d_out;
    unsigned int* rowctr = (unsigned int*)d_ws;

    hipMemsetAsync(rowctr, 0, sizeof(unsigned int), stream);

    dim3 grid(GRID);     // persistent blocks, dynamic row assignment
    dim3 block(256);
    hipLaunchKernelGGL(entmax15_kernel, grid, block, 0, stream,
                       scores, mask, out, rowctr);
}

// Round 3
// 313.611 us; speedup vs baseline: 1.1197x; 1.1197x over previous
//
#include <hip/hip_runtime.h>

// entmax-1.5 over rows of an 8192 x 4096 fp32 matrix, boolean mask (int32).
// R11: R8 compute structure (ballot-compacted candidates, barrier-free
// redundant wave solve -- the proven 117us form) + STRAIGHT-LINE 2-ROW
// PIPELINE, static assignment (grid 4096, block b owns rows 2b, 2b+1).
//
// R10 post-mortem: the persistent-block/dynamic-row pipeline regressed
// (152us) because VGPR_Count=40 proves the allocator did NOT keep the 32
// staged prefetch regs in VGPRs across the loop + asm barriers (scratch
// leakage visible as FETCH +6.6MB / WRITE +3.4MB, VALUBusy 35->26%), plus
// 8192 serialized atomics on one line migrating across 8 XCDs. The MLP idea
// was never actually exercised.
//
// R11 removes every confound: no loop, no atomics, no LDS row broadcast.
// All 16 loads (rows A+B, 32KB/block) issue up front -> 2x bytes in flight;
// A's conversion waits vmcnt(8) only (B keeps flying under A's ~2000cy of
// max/compact/solve/store); B converts after A's epilogue (data long since
// landed; only A's 8 stores outstanding). Intra-block barriers are LDS-only
// (s_waitcnt lgkmcnt(0) + s_barrier; no vmcnt drain -- R10-validated).
// __launch_bounds__(256,5): VGPR cap 102 >> predicted ~80 peak live; chosen
// over (256,6)'s cap 85 because spill (R5/R7/R10) is the proven failure
// mode, not marginal occupancy.

constexpr int NROWS = 8192;
constexpr int NCOL  = 4096;
constexpr int EPT   = 16;   // elements per thread (4096 / 256)
constexpr int NLD   = 4;    // float4/int4 loads per thread per row
constexpr int CAP   = 128;  // candidate slots per wave region
constexpr int MAXIT = 8;    // solve cap; exact-quadratic typically 2-4 iters

static __device__ __forceinline__ int mbcnt64(unsigned long long m) {
    // popcount of m restricted to lanes below this lane
    return __builtin_amdgcn_mbcnt_hi((unsigned)(m >> 32),
           __builtin_amdgcn_mbcnt_lo((unsigned)m, 0));
}

// LDS-only barrier: orders ds ops across the block WITHOUT draining vmcnt --
// in-flight global loads/stores keep flying across it (guide section 5:
// __syncthreads emits s_waitcnt vmcnt(0) before s_barrier, which would kill
// the row-B prefetch). Functionally validated in R10 (passed, same absmax).
static __device__ __forceinline__ void lds_barrier() {
    asm volatile("s_waitcnt lgkmcnt(0)" ::: "memory");
    __builtin_amdgcn_s_barrier();
    asm volatile("" ::: "memory");
}

// Per-row tau solve: row max -> ballot-compacted candidates (z > max-1; only
// those can be in support since tau* >= max-1) -> barrier-free redundant
// wave solve (each wave reads all 512 sentinel-padded slots, stride-64
// conflict-free, and iterates the EXACT piecewise-quadratic root update with
// wave-local butterflies only). 2 LDS barriers per row on the common path.
static __device__ __forceinline__ float process_row(
        const float (&z)[EPT], int tid, int lane, int wave,
        float* cand, float* redA, float* redB, int* ovflp)
{
    // Init: overflow flag + this wave's sentinel slots. Caller guarantees all
    // readers of the previous row's cand/ovfl finished before entry.
    if (tid == 0) *ovflp = 0;
    cand[wave * CAP + lane]      = -1e30f;
    cand[wave * CAP + lane + 64] = -1e30f;

    // Row max: lane tree, wave butterfly, 4-wave LDS combine.
    float mx = z[0];
    #pragma unroll
    for (int i = 1; i < EPT; ++i) mx = fmaxf(mx, z[i]);
    #pragma unroll
    for (int off = 1; off < 64; off <<= 1)
        mx = fmaxf(mx, __shfl_xor(mx, off, 64));
    if (lane == 0) redA[wave] = mx;
    lds_barrier();                    // B1: redA + sentinels + ovfl visible
    mx = fmaxf(fmaxf(redA[0], redA[1]), fmaxf(redA[2], redA[3]));
    const float thresh = mx - 1.0f;   // tau* >= thresh: z <= thresh are dead

    // Compact candidates into this wave's region: 16 ballot rounds.
    int cnt = 0;
    #pragma unroll
    for (int i = 0; i < EPT; ++i) {
        const bool isc = z[i] > thresh;
        const unsigned long long m = __ballot(isc);
        if (isc) {
            const int pos = cnt + mbcnt64(m);
            if (pos < CAP) cand[wave * CAP + pos] = z[i];
        }
        cnt += (int)__popcll(m);      // wave-uniform
    }
    if (lane == 0 && cnt > CAP) *ovflp = 1;
    lds_barrier();                    // B2: compaction visible

    float t = thresh;                 // left bracket: g(thresh) >= 0

    if (*ovflp == 0) {
        // Each wave redundantly reads ALL 512 slots, 8/lane at stride 64
        // (conflict-free); sentinels give d=0. Zero barriers in the loop.
        float cv[8];
        #pragma unroll
        for (int k = 0; k < 8; ++k) cv[k] = cand[k * 64 + lane];

        // Exact piecewise-quadratic iteration: on the support at t,
        // s0 u^2 - 2 s1 u + (s2-1) = 0; u = (s1 - sqrt(disc))/s0 (smaller
        // root); disc<0 -> vertex jump; overshoot self-corrects (u<0).
        #pragma unroll 1
        for (int itr = 0; itr < MAXIT; ++itr) {
            float s0 = 0.f, s1 = 0.f, s2 = 0.f;
            #pragma unroll
            for (int k = 0; k < 8; ++k) {
                const float d = fmaxf(cv[k] - t, 0.f);
                s2 = fmaf(d, d, s2);
                s1 += d;
                s0 += (d > 0.f) ? 1.0f : 0.0f;
            }
            #pragma unroll
            for (int off = 1; off < 64; off <<= 1) {
                s0 += __shfl_xor(s0, off, 64);
                s1 += __shfl_xor(s1, off, 64);
                s2 += __shfl_xor(s2, off, 64);
            }
            const float s0c  = fmaxf(s0, 1.0f);     // s0>=1 at t<=tau*<mx
            const float disc = fmaf(s1, s1, -s0c * (s2 - 1.0f));
            const float u    = (s1 - sqrtf(fmaxf(disc, 0.f))) / s0c;
            t += u;                                  // wave-uniform
            if (__builtin_fabsf(u) < 5e-7f) break;   // wave-uniform break
        }
        // All 4 waves computed bit-identical t from identical data.
    } else {
        // Fallback (pathological rows, >>10 sigma): Newton on full z with
        // block reduction; LDS-only barriers (keep prefetch alive even here).
        #pragma unroll 1
        for (int itr = 0; itr < 10; ++itr) {
            float s2 = 0.f, s1 = 0.f;
            #pragma unroll
            for (int i = 0; i < EPT; ++i) {
                const float d = fmaxf(z[i] - t, 0.f);
                s2 = fmaf(d, d, s2);
                s1 += d;
            }
            #pragma unroll
            for (int off = 1; off < 64; off <<= 1) {
                s2 += __shfl_xor(s2, off, 64);
                s1 += __shfl_xor(s1, off, 64);
            }
            lds_barrier();            // prior-iter redA/redB readers done
            if (lane == 0) { redA[wave] = s1; redB[wave] = s2; }
            lds_barrier();            // sums visible
            s1 = (redA[0] + redA[1]) + (redA[2] + redA[3]);
            s2 = (redB[0] + redB[1]) + (redB[2] + redB[3]);
            const float step = (s2 - 1.0f) / (2.0f * s1);
            t += step;                                  // block-uniform
            if (__builtin_fabsf(step) < 5e-7f) break;   // block-uniform
        }
    }
    return t;
}

static __device__ __forceinline__ void epilogue(
        const float (&z)[EPT], float t, float* __restrict__ orow, int tid)
{
    // p = relu(z - tau)^2, coalesced float4 stores.
    #pragma unroll
    for (int c = 0; c < NLD; ++c) {
        const int base = c * 1024 + tid * 4;
        float4 o;
        float d;
        d = fmaxf(z[c * 4 + 0] - t, 0.f); o.x = d * d;
        d = fmaxf(z[c * 4 + 1] - t, 0.f); o.y = d * d;
        d = fmaxf(z[c * 4 + 2] - t, 0.f); o.z = d * d;
        d = fmaxf(z[c * 4 + 3] - t, 0.f); o.w = d * d;
        *reinterpret_cast<float4*>(orow + base) = o;
    }
}

__global__ __launch_bounds__(256, 5)
void entmax15_kernel(const float* __restrict__ scores,
                     const int*   __restrict__ mask,
                     float*       __restrict__ out)
{
    __shared__ float cand[4 * CAP];   // wave w owns [w*CAP, (w+1)*CAP)
    __shared__ float redA[4], redB[4];
    __shared__ int   ovfl;

    const int tid  = threadIdx.x;
    const int lane = tid & 63;
    const int wave = tid >> 6;
    const int rowA = blockIdx.x * 2;
    const int rowB = rowA + 1;

    // Issue ALL loads up front: rows A and B, 32KB/block in flight.
    float4 psA[NLD]; int4 pmA[NLD];
    float4 psB[NLD]; int4 pmB[NLD];
    {
        const float* sA = scores + (size_t)rowA * NCOL;
        const int*   mA = mask   + (size_t)rowA * NCOL;
        #pragma unroll
        for (int c = 0; c < NLD; ++c) {
            const int base = c * 1024 + tid * 4;
            psA[c] = *reinterpret_cast<const float4*>(sA + base);
            pmA[c] = *reinterpret_cast<const int4*>(mA + base);
        }
        const float* sB = scores + (size_t)rowB * NCOL;
        const int*   mB = mask   + (size_t)rowB * NCOL;
        #pragma unroll
        for (int c = 0; c < NLD; ++c) {
            const int base = c * 1024 + tid * 4;
            psB[c] = *reinterpret_cast<const float4*>(sB + base);
            pmB[c] = *reinterpret_cast<const int4*>(mB + base);
        }
    }

    // Convert A: compiler's wait is vmcnt(8) -- B's 8 loads keep flying
    // under everything until B's conversion.
    float zA[EPT];
    #pragma unroll
    for (int c = 0; c < NLD; ++c) {
        zA[c * 4 + 0] = pmA[c].x ? psA[c].x * 0.5f : -5000.0f;
        zA[c * 4 + 1] = pmA[c].y ? psA[c].y * 0.5f : -5000.0f;
        zA[c * 4 + 2] = pmA[c].z ? psA[c].z * 0.5f : -5000.0f;
        zA[c * 4 + 3] = pmA[c].w ? psA[c].w * 0.5f : -5000.0f;
    }

    const float tA = process_row(zA, tid, lane, wave, cand, redA, redB, &ovfl);
    epilogue(zA, tA, out + (size_t)rowA * NCOL, tid);

    lds_barrier();   // B3: every wave done reading cand/ovfl for row A
                     // (epilogue touches no LDS; A-stores keep flying)

    // Convert B: data landed long ago; only A's 8 stores are outstanding,
    // so the wait here is vmcnt(8) -- no store drain.
    float zB[EPT];
    #pragma unroll
    for (int c = 0; c < NLD; ++c) {
        zB[c * 4 + 0] = pmB[c].x ? psB[c].x * 0.5f : -5000.0f;
        zB[c * 4 + 1] = pmB[c].y ? psB[c].y * 0.5f : -5000.0f;
        zB[c * 4 + 2] = pmB[c].z ? psB[c].z * 0.5f : -5000.0f;
        zB[c * 4 + 3] = pmB[c].w ? psB[c].w * 0.5f : -5000.0f;
    }

    const float tB = process_row(zB, tid, lane, wave, cand, redA, redB, &ovfl);
    epilogue(zB, tB, out + (size_t)rowB * NCOL, tid);
}

extern "C" void kernel_launch(void* const* d_in, const int* in_sizes, int n_in,
                              void* d_out, int out_size, void* d_ws, size_t ws_size,
                              hipStream_t stream)
{
    const float* scores = (const float*)d_in[0];
    const int*   mask   = (const int*)d_in[1];
    float*       out    = (float*)d_out;

    dim3 grid(NROWS / 2);   // block b owns rows 2b, 2b+1
    dim3 block(256);
    hipLaunchKernelGGL(entmax15_kernel, grid, block, 0, stream,
                       scores, mask, out);
}